// Round 2
// baseline (1018.536 us; speedup 1.0000x reference)
//
#include <hip/hip_runtime.h>
#include <hip/hip_bf16.h>

#define T_LEN   8192
#define OBS     32
#define SDIM    5
#define NT      32          // Riccati transient table length (0.32^32 ~ 1e-16)
#define NCHUNK  16
#define LCHUNK  512         // T_LEN / NCHUNK
#define WARM    64          // z warm-up steps
#define BATCH   256

#define COVS_OFF  10485760u   // 256*8192*5
#define LL_OFF    62914560u   // + 256*8192*25

#define WS_CSUM 0
#define WS_TBL  8             // per t: 50 floats (G[25], Mz[25])

__device__ __forceinline__ float readlane_f(float v, int l) {
  return __int_as_float(__builtin_amdgcn_readlane(__float_as_int(v), l));
}

// ---------------------------------------------------------------------------
// Kernel A: data-independent Riccati recursion. Scalar-replicated: every lane
// redundantly runs the 5x5 recursion entirely in registers (no cross-lane ops
// in the loop — the shfl version was ~360us of ds_bpermute latency).
// ---------------------------------------------------------------------------
__global__ __launch_bounds__(64, 1)
void riccati_kernel(const float* __restrict__ Am, const float* __restrict__ Cm,
                    const float* __restrict__ Qld, const float* __restrict__ Rld,
                    float* __restrict__ ws, float* __restrict__ llz)
{
  const int lane = threadIdx.x;
  for (int i = lane; i < BATCH; i += 64) llz[i] = 0.f;   // ll accumulators

  float A[25], B[25], P[25];
  #pragma unroll
  for (int e = 0; e < 25; ++e) A[e] = Am[e];
  #pragma unroll
  for (int e = 0; e < 25; ++e) B[e] = 0.f;
  float sumR = 0.f;
  for (int o = 0; o < OBS; ++o) {
    const float rl = Rld[o];
    sumR += rl;
    const float rv = expf(-rl);
    float co[5];
    #pragma unroll
    for (int s = 0; s < 5; ++s) co[s] = Cm[o*5+s];
    #pragma unroll
    for (int i = 0; i < 5; ++i)
      #pragma unroll
      for (int j = 0; j < 5; ++j) B[i*5+j] = fmaf(rv*co[i], co[j], B[i*5+j]);
  }
  float Qd[5];
  #pragma unroll
  for (int s = 0; s < 5; ++s) Qd[s] = expf(Qld[s]);
  #pragma unroll
  for (int e = 0; e < 25; ++e) P[e] = (e % 6 == 0) ? 1.f : 0.f;

  double csum = 0.0; float clast = 0.f;
  const float LOG2PI = 1.8378770664093453f;

  for (int t = 0; t < NT; ++t) {
    float U[25], Pp[25], M[25], N[25], G[25];
    #pragma unroll
    for (int i = 0; i < 5; ++i)
      #pragma unroll
      for (int j = 0; j < 5; ++j) {
        float acc = 0.f;
        #pragma unroll
        for (int k = 0; k < 5; ++k) acc = fmaf(A[i*5+k], P[k*5+j], acc);
        U[i*5+j] = acc;
      }
    #pragma unroll
    for (int i = 0; i < 5; ++i)
      #pragma unroll
      for (int j = 0; j < 5; ++j) {
        float acc = (i == j) ? Qd[i] : 0.f;
        #pragma unroll
        for (int k = 0; k < 5; ++k) acc = fmaf(U[i*5+k], A[j*5+k], acc);
        Pp[i*5+j] = acc;
      }
    #pragma unroll
    for (int i = 0; i < 5; ++i)
      #pragma unroll
      for (int j = 0; j < 5; ++j) {
        float acc = (i == j) ? 1.f : 0.f;
        #pragma unroll
        for (int k = 0; k < 5; ++k) acc = fmaf(B[i*5+k], Pp[k*5+j], acc);
        M[i*5+j] = acc;
      }
    #pragma unroll
    for (int e = 0; e < 25; ++e) N[e] = (e % 6 == 0) ? 1.f : 0.f;
    float logdet = 0.f;
    #pragma unroll
    for (int p = 0; p < 5; ++p) {
      const float piv = M[p*5+p];
      const float ip  = 1.f / piv;
      logdet += logf(piv);
      #pragma unroll
      for (int j = 0; j < 5; ++j) { M[p*5+j] *= ip; N[p*5+j] *= ip; }
      #pragma unroll
      for (int r2 = 0; r2 < 5; ++r2) if (r2 != p) {
        const float f = M[r2*5+p];
        #pragma unroll
        for (int j = 0; j < 5; ++j) {
          M[r2*5+j] = fmaf(-f, M[p*5+j], M[r2*5+j]);
          N[r2*5+j] = fmaf(-f, N[p*5+j], N[r2*5+j]);
        }
      }
    }
    #pragma unroll
    for (int i = 0; i < 5; ++i)
      #pragma unroll
      for (int j = 0; j < 5; ++j) {
        float acc = 0.f;
        #pragma unroll
        for (int k = 0; k < 5; ++k) acc = fmaf(Pp[i*5+k], N[k*5+j], acc);
        G[i*5+j] = acc;
      }
    // Mz = (I - G B) A
    #pragma unroll
    for (int i = 0; i < 5; ++i) {
      float Wr[5];
      #pragma unroll
      for (int j = 0; j < 5; ++j) {
        float acc = 0.f;
        #pragma unroll
        for (int k = 0; k < 5; ++k) acc = fmaf(G[i*5+k], B[k*5+j], acc);
        Wr[j] = acc;
      }
      #pragma unroll
      for (int j = 0; j < 5; ++j) {
        float acc = A[i*5+j];
        #pragma unroll
        for (int k = 0; k < 5; ++k) acc = fmaf(-Wr[k], A[k*5+j], acc);
        if (lane == 0) ws[WS_TBL + t*50 + 25 + i*5 + j] = acc;
      }
    }
    if (lane == 0) {
      #pragma unroll
      for (int e = 0; e < 25; ++e) ws[WS_TBL + t*50 + e] = G[e];
    }
    const float ct = -0.5f * (OBS * LOG2PI + sumR + logdet);
    csum += (double)ct; clast = ct;
    #pragma unroll
    for (int e = 0; e < 25; ++e) P[e] = G[e];
  }
  if (lane == 0) ws[WS_CSUM] = (float)(csum + (double)(T_LEN - NT) * (double)clast);
}

// ---------------------------------------------------------------------------
// Kernel B: per (batch, time-chunk) single-wave block.
// ---------------------------------------------------------------------------
__global__ __launch_bounds__(64, 4)
void filter_kernel(const float* __restrict__ y, const float* __restrict__ Am,
                   const float* __restrict__ Cm, const float* __restrict__ Rld,
                   float* __restrict__ out, const float* __restrict__ ws)
{
  const int lane = threadIdx.x;
  const int b  = blockIdx.x >> 4;
  const int ck = blockIdx.x & 15;

  __shared__ float sCwr[OBS][8];   // [o][0..4] = (C^T R^-1) row, [o][5] = Rinv
  __shared__ float sA[25];
  __shared__ float sB[25];
  __shared__ float sG[25];         // steady-state posterior cov (broadcast source)
  __shared__ float sMz[64][25];    // transient Mz table, padded with steady state
  __shared__ float zbuf[64*5];

  if (lane < OBS) {
    const float rv = expf(-Rld[lane]);
    sCwr[lane][5] = rv;
    #pragma unroll
    for (int s = 0; s < SDIM; ++s) sCwr[lane][s] = Cm[lane*SDIM+s] * rv;
  }
  if (lane < 25) sA[lane] = Am[lane];
  __syncthreads();
  if (lane < 25) {
    const int i = lane / 5, j = lane % 5;
    float acc = 0.f;
    for (int o = 0; o < OBS; ++o) acc = fmaf(sCwr[o][i], Cm[o*SDIM+j], acc);
    sB[lane] = acc;
    sG[lane] = ws[WS_TBL + (NT-1)*50 + lane];
  }
  if (ck == 0) {
    for (int it = 0; it < 25; ++it) {
      const int idx = lane + 64*it;          // 0..1599
      const int tt = idx / 25, e = idx % 25;
      const int ts = (tt < NT) ? tt : (NT-1);
      sMz[tt][e] = ws[WS_TBL + ts*50 + 25 + e];
    }
  }
  __syncthreads();

  float Gss[25], Mzss[25];
  #pragma unroll
  for (int e = 0; e < 25; ++e) {
    Gss[e]  = ws[WS_TBL + (NT-1)*50 + e];
    Mzss[e] = ws[WS_TBL + (NT-1)*50 + 25 + e];
  }

  const int t0 = ck * LCHUNK;
  const int tstart = (ck == 0) ? 0 : (t0 - WARM);
  const int ngroups = (t0 + LCHUNK - tstart) >> 6;

  const float* yb = y + (size_t)b * T_LEN * OBS;
  float* st = out + (size_t)b * T_LEN * SDIM;
  float* cv = out + (size_t)COVS_OFF + (size_t)b * T_LEN * 25;

  float zc[5] = {0,0,0,0,0};       // z carried between groups (wave-uniform)
  float llacc = 0.f;

  float4 yv[8];
  {
    const float4* yr = (const float4*)(yb + (size_t)(tstart + lane) * OBS);
    #pragma unroll
    for (int i2 = 0; i2 < 8; ++i2) yv[i2] = yr[i2];
  }

  const int e0 = lane - (lane >= 50 ? 50 : (lane >= 25 ? 25 : 0));   // lane % 25

  for (int g = 0; g < ngroups; ++g) {
    const int tb = tstart + (g << 6);
    const int t  = tb + lane;
    const bool warm   = (tb < t0);             // ck>0, g==0: warm-up only
    const bool transG = (ck == 0) && (g == 0); // transient Riccati region

    // u = C^T R^-1 y_t ; qw = y^T R^-1 y
    float u[5] = {0,0,0,0,0};
    float qw = 0.f;
    #pragma unroll
    for (int o = 0; o < OBS; ++o) {
      const float f = ((const float*)yv)[o];
      const float4 cw4 = *(const float4*)&sCwr[o][0];
      const float2 cw2 = *(const float2*)&sCwr[o][4];
      qw  = fmaf(cw2.y * f, f, qw);
      u[0] = fmaf(cw4.x, f, u[0]);
      u[1] = fmaf(cw4.y, f, u[1]);
      u[2] = fmaf(cw4.z, f, u[2]);
      u[3] = fmaf(cw4.w, f, u[3]);
      u[4] = fmaf(cw2.x, f, u[4]);
    }

    // issue next group's loads now; they complete under the sweep
    if (g + 1 < ngroups) {
      const float4* yr = (const float4*)(yb + (size_t)(tb + 64 + lane) * OBS);
      #pragma unroll
      for (int i2 = 0; i2 < 8; ++i2) yv[i2] = yr[i2];
    }

    // bvec = G_t u
    float bvec[5];
    if (!transG) {
      #pragma unroll
      for (int s2 = 0; s2 < 5; ++s2) {
        float acc = 0.f;
        #pragma unroll
        for (int k = 0; k < 5; ++k) acc = fmaf(Gss[s2*5+k], u[k], acc);
        bvec[s2] = acc;
      }
    } else {
      const float* gp = ws + WS_TBL + (size_t)((t < NT) ? t : (NT-1)) * 50;
      #pragma unroll
      for (int s2 = 0; s2 < 5; ++s2) {
        float acc = 0.f;
        #pragma unroll
        for (int k = 0; k < 5; ++k) acc = fmaf(gp[s2*5+k], u[k], acc);
        bvec[s2] = acc;
      }
    }

    // replicated serial sweep with predicated stop: lane L ends holding z_{tb+L}
    float z[5];
    #pragma unroll
    for (int s2 = 0; s2 < 5; ++s2) z[s2] = zc[s2];
    if (!transG) {
      #pragma unroll 8
      for (int j = 0; j < 64; ++j) {
        float nz[5];
        #pragma unroll
        for (int s2 = 0; s2 < 5; ++s2) {
          float acc = readlane_f(bvec[s2], j);
          #pragma unroll
          for (int k = 0; k < 5; ++k) acc = fmaf(Mzss[s2*5+k], z[k], acc);
          nz[s2] = acc;
        }
        #pragma unroll
        for (int s2 = 0; s2 < 5; ++s2) z[s2] = (lane >= j) ? nz[s2] : z[s2];
      }
    } else {
      #pragma unroll 4
      for (int j = 0; j < 64; ++j) {
        float nz[5];
        #pragma unroll
        for (int s2 = 0; s2 < 5; ++s2) {
          float acc = readlane_f(bvec[s2], j);
          #pragma unroll
          for (int k = 0; k < 5; ++k) acc = fmaf(sMz[j][s2*5+k], z[k], acc);
          nz[s2] = acc;
        }
        #pragma unroll
        for (int s2 = 0; s2 < 5; ++s2) z[s2] = (lane >= j) ? nz[s2] : z[s2];
      }
    }

    // zprev via shfl_up; carry via lane 63
    float zprev[5];
    #pragma unroll
    for (int s2 = 0; s2 < 5; ++s2) {
      const float v = __shfl_up(z[s2], 1);
      zprev[s2] = (lane == 0) ? zc[s2] : v;
    }
    #pragma unroll
    for (int s2 = 0; s2 < 5; ++s2) zc[s2] = readlane_f(z[s2], 63);

    if (!warm) {
      // z_pred = A z_{t-1}
      float zp[5];
      #pragma unroll
      for (int s2 = 0; s2 < 5; ++s2) {
        float acc = 0.f;
        #pragma unroll
        for (int k = 0; k < 5; ++k) acc = fmaf(sA[s2*5+k], zprev[k], acc);
        zp[s2] = acc;
      }
      float w[5], zBz = 0.f, uzp = 0.f;
      #pragma unroll
      for (int s2 = 0; s2 < 5; ++s2) {
        float bz = 0.f;
        #pragma unroll
        for (int k = 0; k < 5; ++k) bz = fmaf(sB[s2*5+k], zp[k], bz);
        w[s2] = u[s2] - bz;
        zBz = fmaf(zp[s2], bz, zBz);
        uzp = fmaf(u[s2], zp[s2], uzp);
      }
      const float vRv = qw - 2.f*uzp + zBz;
      float wGw = 0.f;
      if (!transG) {
        #pragma unroll
        for (int i2 = 0; i2 < 5; ++i2)
          #pragma unroll
          for (int k = 0; k < 5; ++k) wGw = fmaf(Gss[i2*5+k]*w[i2], w[k], wGw);
      } else {
        const float* gp = ws + WS_TBL + (size_t)((t < NT) ? t : (NT-1)) * 50;
        #pragma unroll
        for (int i2 = 0; i2 < 5; ++i2)
          #pragma unroll
          for (int k = 0; k < 5; ++k) wGw = fmaf(gp[i2*5+k]*w[i2], w[k], wGw);
      }
      llacc += vRv - wGw;

      // states: LDS-stage then dense coalesced stores
      #pragma unroll
      for (int s2 = 0; s2 < 5; ++s2) zbuf[lane*5 + s2] = z[s2];
      float* stg = st + (size_t)tb * 5;
      #pragma unroll
      for (int k = 0; k < 5; ++k) stg[lane + 64*k] = zbuf[lane + 64*k];

      // covs
      if (!transG) {
        float* cvg = cv + (size_t)tb * 25;
        int e = e0;
        #pragma unroll
        for (int k = 0; k < 25; ++k) {
          cvg[lane + 64*k] = sG[e];                 // dense 256B/instr stores
          e += 14; if (e >= 25) e -= 25;            // (lane+64k) % 25 walk
        }
      } else {
        const float* gp = ws + WS_TBL + (size_t)((t < NT) ? t : (NT-1)) * 50;
        #pragma unroll
        for (int e = 0; e < 25; ++e) cv[(size_t)t*25 + e] = gp[e];
      }
    }
  }

  #pragma unroll
  for (int off = 32; off >= 1; off >>= 1) llacc += __shfl_down(llacc, off);
  if (lane == 0) {
    float v = -0.5f * llacc;
    if (ck == 0) v += ws[WS_CSUM];
    atomicAdd(out + (size_t)LL_OFF + b, v);
  }
}

extern "C" void kernel_launch(void* const* d_in, const int* in_sizes, int n_in,
                              void* d_out, int out_size, void* d_ws, size_t ws_size,
                              hipStream_t stream) {
  const float* y   = (const float*)d_in[0];
  const float* A   = (const float*)d_in[1];
  const float* C   = (const float*)d_in[2];
  const float* Qld = (const float*)d_in[3];
  const float* Rld = (const float*)d_in[4];
  float* out = (float*)d_out;
  float* ws  = (float*)d_ws;

  riccati_kernel<<<1, 64, 0, stream>>>(A, C, Qld, Rld, ws, out + (size_t)LL_OFF);
  filter_kernel<<<BATCH*NCHUNK, 64, 0, stream>>>(y, A, C, Rld, out, ws);
}

// Round 3
// 742.172 us; speedup vs baseline: 1.3724x; 1.3724x over previous
//
#include <hip/hip_runtime.h>
#include <hip/hip_bf16.h>

#define T_LEN   8192
#define OBS     32
#define SDIM    5
#define NT      32          // Riccati transient length (contraction ~0.32/step)
#define NCHUNK  16
#define LCHUNK  512         // T_LEN / NCHUNK
#define WARM    64
#define BATCH   256

#define COVS_OFF  10485760u   // 256*8192*5
#define LL_OFF    62914560u   // + 256*8192*25

#define WS_CSUM 0
#define WS_TBL  8                 // per t: 50 floats (G[25], Mz[25])
#define WS_B    (WS_TBL + NT*50)  // B = C^T R^-1 C (25 floats)

__device__ __forceinline__ float readlane_f(float v, int l) {
  return __int_as_float(__builtin_amdgcn_readlane(__float_as_int(v), l));
}

// ---------------------------------------------------------------------------
// Kernel A: data-independent Riccati recursion, scalar-replicated in registers.
// ---------------------------------------------------------------------------
__global__ __launch_bounds__(64, 1)
void riccati_kernel(const float* __restrict__ Am, const float* __restrict__ Cm,
                    const float* __restrict__ Qld, const float* __restrict__ Rld,
                    float* __restrict__ ws, float* __restrict__ llz)
{
  const int lane = threadIdx.x;
  for (int i = lane; i < BATCH; i += 64) llz[i] = 0.f;

  float A[25], B[25], P[25];
  #pragma unroll
  for (int e = 0; e < 25; ++e) A[e] = Am[e];
  #pragma unroll
  for (int e = 0; e < 25; ++e) B[e] = 0.f;
  float sumR = 0.f;
  for (int o = 0; o < OBS; ++o) {
    const float rl = Rld[o];
    sumR += rl;
    const float rv = expf(-rl);
    float co[5];
    #pragma unroll
    for (int s = 0; s < 5; ++s) co[s] = Cm[o*5+s];
    #pragma unroll
    for (int i = 0; i < 5; ++i)
      #pragma unroll
      for (int j = 0; j < 5; ++j) B[i*5+j] = fmaf(rv*co[i], co[j], B[i*5+j]);
  }
  float Qd[5];
  #pragma unroll
  for (int s = 0; s < 5; ++s) Qd[s] = expf(Qld[s]);
  #pragma unroll
  for (int e = 0; e < 25; ++e) P[e] = (e % 6 == 0) ? 1.f : 0.f;

  if (lane == 0) {
    #pragma unroll
    for (int e = 0; e < 25; ++e) ws[WS_B + e] = B[e];
  }

  double csum = 0.0; float clast = 0.f;
  const float LOG2PI = 1.8378770664093453f;

  for (int t = 0; t < NT; ++t) {
    float U[25], Pp[25], M[25], N[25], G[25];
    #pragma unroll
    for (int i = 0; i < 5; ++i)
      #pragma unroll
      for (int j = 0; j < 5; ++j) {
        float acc = 0.f;
        #pragma unroll
        for (int k = 0; k < 5; ++k) acc = fmaf(A[i*5+k], P[k*5+j], acc);
        U[i*5+j] = acc;
      }
    #pragma unroll
    for (int i = 0; i < 5; ++i)
      #pragma unroll
      for (int j = 0; j < 5; ++j) {
        float acc = (i == j) ? Qd[i] : 0.f;
        #pragma unroll
        for (int k = 0; k < 5; ++k) acc = fmaf(U[i*5+k], A[j*5+k], acc);
        Pp[i*5+j] = acc;
      }
    #pragma unroll
    for (int i = 0; i < 5; ++i)
      #pragma unroll
      for (int j = 0; j < 5; ++j) {
        float acc = (i == j) ? 1.f : 0.f;
        #pragma unroll
        for (int k = 0; k < 5; ++k) acc = fmaf(B[i*5+k], Pp[k*5+j], acc);
        M[i*5+j] = acc;
      }
    #pragma unroll
    for (int e = 0; e < 25; ++e) N[e] = (e % 6 == 0) ? 1.f : 0.f;
    float logdet = 0.f;
    #pragma unroll
    for (int p = 0; p < 5; ++p) {
      const float piv = M[p*5+p];
      const float ip  = 1.f / piv;
      logdet += logf(piv);
      #pragma unroll
      for (int j = 0; j < 5; ++j) { M[p*5+j] *= ip; N[p*5+j] *= ip; }
      #pragma unroll
      for (int r2 = 0; r2 < 5; ++r2) if (r2 != p) {
        const float f = M[r2*5+p];
        #pragma unroll
        for (int j = 0; j < 5; ++j) {
          M[r2*5+j] = fmaf(-f, M[p*5+j], M[r2*5+j]);
          N[r2*5+j] = fmaf(-f, N[p*5+j], N[r2*5+j]);
        }
      }
    }
    #pragma unroll
    for (int i = 0; i < 5; ++i)
      #pragma unroll
      for (int j = 0; j < 5; ++j) {
        float acc = 0.f;
        #pragma unroll
        for (int k = 0; k < 5; ++k) acc = fmaf(Pp[i*5+k], N[k*5+j], acc);
        G[i*5+j] = acc;
      }
    #pragma unroll
    for (int i = 0; i < 5; ++i) {
      float Wr[5];
      #pragma unroll
      for (int j = 0; j < 5; ++j) {
        float acc = 0.f;
        #pragma unroll
        for (int k = 0; k < 5; ++k) acc = fmaf(G[i*5+k], B[k*5+j], acc);
        Wr[j] = acc;
      }
      #pragma unroll
      for (int j = 0; j < 5; ++j) {
        float acc = A[i*5+j];
        #pragma unroll
        for (int k = 0; k < 5; ++k) acc = fmaf(-Wr[k], A[k*5+j], acc);
        if (lane == 0) ws[WS_TBL + t*50 + 25 + i*5 + j] = acc;
      }
    }
    if (lane == 0) {
      #pragma unroll
      for (int e = 0; e < 25; ++e) ws[WS_TBL + t*50 + e] = G[e];
    }
    const float ct = -0.5f * (OBS * LOG2PI + sumR + logdet);
    csum += (double)ct; clast = ct;
    #pragma unroll
    for (int e = 0; e < 25; ++e) P[e] = G[e];
  }
  if (lane == 0) ws[WS_CSUM] = (float)(csum + (double)(T_LEN - NT) * (double)clast);
}

// ---------------------------------------------------------------------------
// Kernel B: one wave per (batch, time-chunk). y staged via global_load_lds with
// pre-swizzled per-lane global source (XOR involution, linear LDS dest, G21);
// rows read back with swizzled ds_read_b128 (8-way instead of 64-way conflict).
// ---------------------------------------------------------------------------
__global__ __launch_bounds__(64, 4)
void filter_kernel(const float* __restrict__ y, const float* __restrict__ Am,
                   const float* __restrict__ Cm, const float* __restrict__ Rld,
                   float* __restrict__ out, const float* __restrict__ ws)
{
  const int lane = threadIdx.x;
  const int b  = blockIdx.x >> 4;
  const int ck = blockIdx.x & 15;

  __shared__ float sY[2048];       // 8 KB: 64 rows x 128 B, column-swizzled
  __shared__ float sCwr[OBS][8];   // [o][0..4]=(C^T R^-1) row, [o][5]=Rinv
  __shared__ float sG[32];         // steady posterior cov (per-lane-index source)
  __shared__ float zbuf[64*5];

  if (lane < OBS) {
    const float rv = expf(-Rld[lane]);
    sCwr[lane][5] = rv;
    #pragma unroll
    for (int s = 0; s < SDIM; ++s) sCwr[lane][s] = Cm[lane*SDIM+s] * rv;
  }
  if (lane < 25) sG[lane] = ws[WS_TBL + (NT-1)*50 + lane];
  __syncthreads();

  // wave-uniform tables -> scalar registers (uniform addresses => s_load)
  float As[25], Bs[25], Gss[25], Mzss[25];
  #pragma unroll
  for (int e = 0; e < 25; ++e) {
    As[e]   = Am[e];
    Bs[e]   = ws[WS_B + e];
    Gss[e]  = ws[WS_TBL + (NT-1)*50 + e];
    Mzss[e] = ws[WS_TBL + (NT-1)*50 + 25 + e];
  }

  const int t0 = ck * LCHUNK;
  const int tstart = (ck == 0) ? 0 : (t0 - WARM);
  const int ngroups = (t0 + LCHUNK - tstart) >> 6;

  const char* yb8 = (const char*)(y + (size_t)b * T_LEN * OBS);
  float* st = out + (size_t)b * T_LEN * SDIM;
  float* cv = out + (size_t)COVS_OFF + (size_t)b * T_LEN * 25;

  const int q  = lane >> 3;
  const int r7 = lane & 7;
  const int laneoff = q*128 + 16*(r7 ^ q);   // inverse-swizzle source offset
  const int e0 = lane - (lane >= 50 ? 50 : (lane >= 25 ? 25 : 0));   // lane % 25

  #define STAGE(tbb) do { \
    const char* gp0 = yb8 + (size_t)(tbb)*128 + laneoff; \
    _Pragma("unroll") \
    for (int i = 0; i < 8; ++i) \
      __builtin_amdgcn_global_load_lds( \
        (const __attribute__((address_space(1))) void*)(gp0 + i*1024), \
        (__attribute__((address_space(3))) void*)((char*)&sY[0] + i*1024), 16, 0, 0); \
  } while (0)

  float zc[5] = {0,0,0,0,0};
  float llacc = 0.f;

  STAGE(tstart);

  for (int g = 0; g < ngroups; ++g) {
    const int tb = tstart + (g << 6);
    const int t  = tb + lane;
    const bool warm   = (tb < t0);
    const bool transG = (ck == 0) && (g == 0);

    asm volatile("s_waitcnt vmcnt(0)" ::: "memory");   // stage(g) landed
    __builtin_amdgcn_sched_barrier(0);

    // my row from LDS (swizzled) -> 8 x ds_read_b128
    float4 row[8];
    #pragma unroll
    for (int i2 = 0; i2 < 8; ++i2)
      row[i2] = *(const float4*)((const char*)&sY[0] + (lane*128 + ((16*i2) ^ (r7*16))));
    asm volatile("s_waitcnt lgkmcnt(0)" ::: "memory"); // rows in regs before overwrite
    __builtin_amdgcn_sched_barrier(0);

    if (g + 1 < ngroups) STAGE(tb + 64);               // lands under the sweep

    // u = C^T R^-1 y_t ; qw = y^T R^-1 y
    float u[5] = {0,0,0,0,0};
    float qw = 0.f;
    #pragma unroll
    for (int i2 = 0; i2 < 8; ++i2) {
      const float f0 = row[i2].x, f1 = row[i2].y, f2 = row[i2].z, f3 = row[i2].w;
      const float fv[4] = {f0, f1, f2, f3};
      #pragma unroll
      for (int k = 0; k < 4; ++k) {
        const int o = i2*4 + k;
        const float f = fv[k];
        const float4 cw4 = *(const float4*)&sCwr[o][0];
        const float2 cw2 = *(const float2*)&sCwr[o][4];
        qw  = fmaf(cw2.y * f, f, qw);
        u[0] = fmaf(cw4.x, f, u[0]);
        u[1] = fmaf(cw4.y, f, u[1]);
        u[2] = fmaf(cw4.z, f, u[2]);
        u[3] = fmaf(cw2.x * 0.f + cw4.w, f, u[3]);
        u[4] = fmaf(cw2.x, f, u[4]);
      }
    }

    // bvec = G_t u
    float bvec[5];
    if (!transG) {
      #pragma unroll
      for (int s2 = 0; s2 < 5; ++s2) {
        float acc = 0.f;
        #pragma unroll
        for (int k = 0; k < 5; ++k) acc = fmaf(Gss[s2*5+k], u[k], acc);
        bvec[s2] = acc;
      }
    } else {
      const float* gp = ws + WS_TBL + (size_t)((t < NT) ? t : (NT-1)) * 50;
      #pragma unroll
      for (int s2 = 0; s2 < 5; ++s2) {
        float acc = 0.f;
        #pragma unroll
        for (int k = 0; k < 5; ++k) acc = fmaf(gp[s2*5+k], u[k], acc);
        bvec[s2] = acc;
      }
    }

    // replicated serial sweep; lane L freezes at z_{tb+L}
    float z[5];
    #pragma unroll
    for (int s2 = 0; s2 < 5; ++s2) z[s2] = zc[s2];
    if (!transG) {
      #pragma unroll 8
      for (int j = 0; j < 64; ++j) {
        float nz[5];
        #pragma unroll
        for (int s2 = 0; s2 < 5; ++s2) {
          float acc = readlane_f(bvec[s2], j);
          #pragma unroll
          for (int k = 0; k < 5; ++k) acc = fmaf(Mzss[s2*5+k], z[k], acc);
          nz[s2] = acc;
        }
        #pragma unroll
        for (int s2 = 0; s2 < 5; ++s2) z[s2] = (lane >= j) ? nz[s2] : z[s2];
      }
    } else {
      for (int j = 0; j < 64; ++j) {
        const float* mzp = ws + WS_TBL + (size_t)((j < NT) ? j : (NT-1)) * 50 + 25;
        float nz[5];
        #pragma unroll
        for (int s2 = 0; s2 < 5; ++s2) {
          float acc = readlane_f(bvec[s2], j);
          #pragma unroll
          for (int k = 0; k < 5; ++k) acc = fmaf(mzp[s2*5+k], z[k], acc);
          nz[s2] = acc;
        }
        #pragma unroll
        for (int s2 = 0; s2 < 5; ++s2) z[s2] = (lane >= j) ? nz[s2] : z[s2];
      }
    }

    float zprev[5];
    #pragma unroll
    for (int s2 = 0; s2 < 5; ++s2) {
      const float v = __shfl_up(z[s2], 1);
      zprev[s2] = (lane == 0) ? zc[s2] : v;
    }
    #pragma unroll
    for (int s2 = 0; s2 < 5; ++s2) zc[s2] = readlane_f(z[s2], 63);

    if (!warm) {
      float zp[5];
      #pragma unroll
      for (int s2 = 0; s2 < 5; ++s2) {
        float acc = 0.f;
        #pragma unroll
        for (int k = 0; k < 5; ++k) acc = fmaf(As[s2*5+k], zprev[k], acc);
        zp[s2] = acc;
      }
      float w[5], zBz = 0.f, uzp = 0.f;
      #pragma unroll
      for (int s2 = 0; s2 < 5; ++s2) {
        float bz = 0.f;
        #pragma unroll
        for (int k = 0; k < 5; ++k) bz = fmaf(Bs[s2*5+k], zp[k], bz);
        w[s2] = u[s2] - bz;
        zBz = fmaf(zp[s2], bz, zBz);
        uzp = fmaf(u[s2], zp[s2], uzp);
      }
      const float vRv = qw - 2.f*uzp + zBz;
      float wGw = 0.f;
      if (!transG) {
        #pragma unroll
        for (int i2 = 0; i2 < 5; ++i2)
          #pragma unroll
          for (int k = 0; k < 5; ++k) wGw = fmaf(Gss[i2*5+k]*w[i2], w[k], wGw);
      } else {
        const float* gp = ws + WS_TBL + (size_t)((t < NT) ? t : (NT-1)) * 50;
        #pragma unroll
        for (int i2 = 0; i2 < 5; ++i2)
          #pragma unroll
          for (int k = 0; k < 5; ++k) wGw = fmaf(gp[i2*5+k]*w[i2], w[k], wGw);
      }
      llacc += vRv - wGw;

      // coalesced state stores via LDS transpose
      #pragma unroll
      for (int s2 = 0; s2 < 5; ++s2) zbuf[lane*5 + s2] = z[s2];
      float* stg = st + (size_t)tb * 5;
      #pragma unroll
      for (int k = 0; k < 5; ++k) stg[lane + 64*k] = zbuf[lane + 64*k];

      if (!transG) {
        float* cvg = cv + (size_t)tb * 25;
        int e = e0;
        #pragma unroll
        for (int k = 0; k < 25; ++k) {
          cvg[lane + 64*k] = sG[e];
          e += 14; if (e >= 25) e -= 25;
        }
      } else {
        const float* gp = ws + WS_TBL + (size_t)((t < NT) ? t : (NT-1)) * 50;
        #pragma unroll
        for (int e = 0; e < 25; ++e) cv[(size_t)t*25 + e] = gp[e];
      }
    }
  }
  #undef STAGE

  #pragma unroll
  for (int off = 32; off >= 1; off >>= 1) llacc += __shfl_down(llacc, off);
  if (lane == 0) {
    float v = -0.5f * llacc;
    if (ck == 0) v += ws[WS_CSUM];
    atomicAdd(out + (size_t)LL_OFF + b, v);
  }
}

extern "C" void kernel_launch(void* const* d_in, const int* in_sizes, int n_in,
                              void* d_out, int out_size, void* d_ws, size_t ws_size,
                              hipStream_t stream) {
  const float* y   = (const float*)d_in[0];
  const float* A   = (const float*)d_in[1];
  const float* C   = (const float*)d_in[2];
  const float* Qld = (const float*)d_in[3];
  const float* Rld = (const float*)d_in[4];
  float* out = (float*)d_out;
  float* ws  = (float*)d_ws;

  riccati_kernel<<<1, 64, 0, stream>>>(A, C, Qld, Rld, ws, out + (size_t)LL_OFF);
  filter_kernel<<<BATCH*NCHUNK, 64, 0, stream>>>(y, A, C, Rld, out, ws);
}